// Round 1
// baseline (594.626 us; speedup 1.0000x reference)
//
#include <hip/hip_runtime.h>

typedef _Float16 f16;
typedef _Float16 half8 __attribute__((ext_vector_type(8)));
typedef _Float16 half4 __attribute__((ext_vector_type(4)));
typedef float floatx4 __attribute__((ext_vector_type(4)));

#define MFMA16(a, b, c) __builtin_amdgcn_mfma_f32_16x16x32_f16(a, b, c, 0, 0, 0)

union H8 { half8 v; f16 e[8]; };

static constexpr int SEQ = 2048;
static constexpr int DIM = 512;

// ---------------------------------------------------------------------------
// Kernel 1: q = query @ W_in^T  (fp32 inputs -> fp16 q)
// Writes q into comb[:, 512:1024] (row-major) and qT [B][512][2048].
// 128x128 C-tile, BK=32, 4 waves each 64x64 (4x4 of 16x16x32 MFMA).
// ---------------------------------------------------------------------------
__global__ __launch_bounds__(256) void k_qin(const float* __restrict__ query,
                                             const float* __restrict__ W_in,
                                             f16* __restrict__ comb,
                                             f16* __restrict__ qT)
{
    __shared__ f16 At[128][40];   // +8 pad: 2-way banks only
    __shared__ f16 Bt[128][40];
    __shared__ f16 Ct[128][136];  // C routed through LDS for coalesced stores
    const int tid  = threadIdx.x;
    const int lane = tid & 63;
    const int w    = tid >> 6;
    const int l15  = lane & 15;
    const int quad = lane >> 4;
    const int mbase = blockIdx.y * 128;
    const int nbase = blockIdx.x * 128;
    const int wm = (w & 1) * 64, wn = (w >> 1) * 64;

    floatx4 acc[4][4];
#pragma unroll
    for (int i = 0; i < 4; ++i)
#pragma unroll
        for (int j = 0; j < 4; ++j) acc[i][j] = (floatx4)0.f;

    for (int k0 = 0; k0 < DIM; k0 += 32) {
        // stage A (query) and B (W_in) fp32->fp16; 128 rows x 8 float4 chunks
#pragma unroll
        for (int it = 0; it < 4; ++it) {
            int c = it * 256 + tid;
            int r = c >> 3, cc = (c & 7) << 2;
            float4 va = *reinterpret_cast<const float4*>(query + (size_t)(mbase + r) * DIM + k0 + cc);
            half4 ha = {(f16)va.x, (f16)va.y, (f16)va.z, (f16)va.w};
            *reinterpret_cast<half4*>(&At[r][cc]) = ha;
            float4 vb = *reinterpret_cast<const float4*>(W_in + (size_t)(nbase + r) * DIM + k0 + cc);
            half4 hb = {(f16)vb.x, (f16)vb.y, (f16)vb.z, (f16)vb.w};
            *reinterpret_cast<half4*>(&Bt[r][cc]) = hb;
        }
        __syncthreads();
        half8 a[4], b[4];
#pragma unroll
        for (int i = 0; i < 4; ++i) a[i] = *reinterpret_cast<half8*>(&At[wm + i * 16 + l15][quad * 8]);
#pragma unroll
        for (int j = 0; j < 4; ++j) b[j] = *reinterpret_cast<half8*>(&Bt[wn + j * 16 + l15][quad * 8]);
#pragma unroll
        for (int i = 0; i < 4; ++i)
#pragma unroll
            for (int j = 0; j < 4; ++j)
                acc[i][j] = MFMA16(a[i], b[j], acc[i][j]);
        __syncthreads();
    }
    // C -> LDS as fp16. C/D layout: col = lane&15, row = quad*4 + reg.
#pragma unroll
    for (int i = 0; i < 4; ++i)
#pragma unroll
        for (int j = 0; j < 4; ++j)
#pragma unroll
            for (int r = 0; r < 4; ++r)
                Ct[wm + i * 16 + quad * 4 + r][wn + j * 16 + l15] = (f16)acc[i][j][r];
    __syncthreads();
    const int bb = mbase >> 11;    // batch
    const int tb = mbase & 2047;   // token base within batch
    // q row-major -> comb[:, 512:]
#pragma unroll
    for (int it = 0; it < 8; ++it) {
        int c = it * 256 + tid;
        int r = c >> 4, c8 = (c & 15) << 3;
        *reinterpret_cast<half8*>(comb + (size_t)(mbase + r) * 1024 + 512 + nbase + c8) =
            *reinterpret_cast<half8*>(&Ct[r][c8]);
    }
    // qT[b][d][token]
#pragma unroll
    for (int it = 0; it < 8; ++it) {
        int c = it * 256 + tid;
        int col = c & 127, rc = (c >> 7) << 3;
        H8 hv;
#pragma unroll
        for (int r8 = 0; r8 < 8; ++r8) hv.e[r8] = Ct[rc + r8][col];
        *reinterpret_cast<half8*>(qT + ((size_t)bb * DIM + nbase + col) * SEQ + tb + rc) = hv.v;
    }
}

// ---------------------------------------------------------------------------
// Kernel 2: fused causal attention (strictly-lower mask; K = V = q).
// Block = 4 waves, 64 Q rows (wave owns 16). Q A-frags in registers.
// Kt [64][520] fp16 + VT [512][72] fp16 + Pbuf [4][16][72] = 149504 B dyn LDS.
// ---------------------------------------------------------------------------
__global__ __launch_bounds__(256, 1) void k_attn(const f16* __restrict__ qT,
                                                 f16* __restrict__ comb)
{
    extern __shared__ f16 sm[];
    f16* Kt = sm;                 // [64][520]
    f16* VT = sm + 64 * 520;      // [512][72]
    f16* Pb = VT + 512 * 72;      // [4][16][72]
    const int tid  = threadIdx.x;
    const int lane = tid & 63;
    const int w    = tid >> 6;
    const int l15  = lane & 15;
    const int quad = lane >> 4;
    const int qtile = blockIdx.x;
    const int b     = blockIdx.y;
    const f16* combq = comb + (size_t)b * SEQ * 1024 + 512;  // q half
    const int myqrow = qtile * 64 + w * 16 + l15;

    // Q A-fragments for all 16 k-steps: A[m=lane&15][k=quad*8+j]
    half8 qf[16];
#pragma unroll
    for (int ks = 0; ks < 16; ++ks)
        qf[ks] = *reinterpret_cast<const half8*>(combq + (size_t)myqrow * 1024 + ks * 32 + quad * 8);

    floatx4 acc[32];
#pragma unroll
    for (int nt = 0; nt < 32; ++nt) acc[nt] = (floatx4)0.f;
    float mrow[4] = {-1e38f, -1e38f, -1e38f, -1e38f};
    float lrow[4] = {0.f, 0.f, 0.f, 0.f};
    f16* Pw = Pb + w * (16 * 72);

    for (int kvt = 0; kvt <= qtile; ++kvt) {
        __syncthreads();  // previous iteration's LDS readers done
        // stage Kt: 64 kv rows x 512 d (row stride 520 halfs)
#pragma unroll
        for (int it = 0; it < 16; ++it) {
            int c = it * 256 + tid;
            int rr = c >> 6, c8 = (c & 63) << 3;
            half8 v = *reinterpret_cast<const half8*>(combq + (size_t)(kvt * 64 + rr) * 1024 + c8);
            *reinterpret_cast<half8*>(Kt + rr * 520 + c8) = v;
        }
        // stage VT: 512 d rows x 64 kv (row stride 72 halfs) from qT
#pragma unroll
        for (int it = 0; it < 16; ++it) {
            int c = it * 256 + tid;
            int d = c >> 3, c8 = (c & 7) << 3;
            half8 v = *reinterpret_cast<const half8*>(qT + ((size_t)b * DIM + d) * SEQ + kvt * 64 + c8);
            *reinterpret_cast<half8*>(VT + d * 72 + c8) = v;
        }
        __syncthreads();
        // S = Q * K^T : s[nt] covers kv cols nt*16..+15
        floatx4 s[4];
#pragma unroll
        for (int nt = 0; nt < 4; ++nt) s[nt] = (floatx4)0.f;
#pragma unroll
        for (int ks = 0; ks < 16; ++ks) {
#pragma unroll
            for (int nt = 0; nt < 4; ++nt) {
                half8 bf = *reinterpret_cast<const half8*>(Kt + (nt * 16 + l15) * 520 + ks * 32 + quad * 8);
                s[nt] = MFMA16(qf[ks], bf, s[nt]);
            }
        }
        // causal mask on diagonal tile: kv >= qrow masked (incl. diagonal)
        if (kvt == qtile) {
#pragma unroll
            for (int nt = 0; nt < 4; ++nt)
#pragma unroll
                for (int r = 0; r < 4; ++r)
                    if (nt * 16 + l15 >= w * 16 + quad * 4 + r) s[nt][r] = -1e38f;
        }
        // online softmax per row r (rows quad*4+r; stats shared across 16-lane group)
#pragma unroll
        for (int r = 0; r < 4; ++r) {
            float mx = fmaxf(fmaxf(s[0][r], s[1][r]), fmaxf(s[2][r], s[3][r]));
#pragma unroll
            for (int msk = 8; msk >= 1; msk >>= 1) mx = fmaxf(mx, __shfl_xor(mx, msk));
            float mnew = fmaxf(mrow[r], mx);
            float alpha = __expf(mrow[r] - mnew);   // finite sentinels: no NaN
            float ps = 0.f;
#pragma unroll
            for (int nt = 0; nt < 4; ++nt) {
                float p = __expf(s[nt][r] - mnew);
                ps += p;
                Pw[(quad * 4 + r) * 72 + nt * 16 + l15] = (f16)p;
            }
#pragma unroll
            for (int msk = 8; msk >= 1; msk >>= 1) ps += __shfl_xor(ps, msk);
            lrow[r] = lrow[r] * alpha + ps;
            mrow[r] = mnew;
#pragma unroll
            for (int nt = 0; nt < 32; ++nt) acc[nt][r] *= alpha;
        }
        // P -> A-operand layout via per-wave LDS round-trip (same-wave: lgkmcnt only)
        half8 pf0 = *reinterpret_cast<half8*>(Pw + l15 * 72 + quad * 8);
        half8 pf1 = *reinterpret_cast<half8*>(Pw + l15 * 72 + 32 + quad * 8);
        // O += P * V ; V B-frags contiguous in VT[d][kv]
#pragma unroll
        for (int nt = 0; nt < 32; ++nt) {
            half8 v0 = *reinterpret_cast<const half8*>(VT + (nt * 16 + l15) * 72 + quad * 8);
            acc[nt] = MFMA16(pf0, v0, acc[nt]);
            half8 v1 = *reinterpret_cast<const half8*>(VT + (nt * 16 + l15) * 72 + 32 + quad * 8);
            acc[nt] = MFMA16(pf1, v1, acc[nt]);
        }
    }
    // epilogue: mix = O / l -> comb[:, 0:512]; row 0 forced to zero (torch zeroes it)
    f16* combm = comb + (size_t)b * SEQ * 1024;
#pragma unroll
    for (int r = 0; r < 4; ++r) {
        int qr = qtile * 64 + w * 16 + quad * 4 + r;
        float inv = (qr == 0 || lrow[r] <= 0.f) ? 0.f : 1.f / lrow[r];
#pragma unroll
        for (int nt = 0; nt < 32; ++nt)
            combm[(size_t)qr * 1024 + nt * 16 + l15] = (f16)(acc[nt][r] * inv);
    }
}

// ---------------------------------------------------------------------------
// Kernel 3: out = comb[32768,1024] @ W_out^T -> fp32 [32768,512]
// ---------------------------------------------------------------------------
__global__ __launch_bounds__(256) void k_out(const f16* __restrict__ comb,
                                             const float* __restrict__ W_out,
                                             float* __restrict__ out)
{
    __shared__ f16 At[128][40];
    __shared__ f16 Bt[128][40];
    const int tid  = threadIdx.x;
    const int lane = tid & 63;
    const int w    = tid >> 6;
    const int l15  = lane & 15;
    const int quad = lane >> 4;
    const int mbase = blockIdx.y * 128;
    const int nbase = blockIdx.x * 128;
    const int wm = (w & 1) * 64, wn = (w >> 1) * 64;

    floatx4 acc[4][4];
#pragma unroll
    for (int i = 0; i < 4; ++i)
#pragma unroll
        for (int j = 0; j < 4; ++j) acc[i][j] = (floatx4)0.f;

    for (int k0 = 0; k0 < 1024; k0 += 32) {
        // A: fp16 already; 128 rows x 4 chunks of 8 halfs
#pragma unroll
        for (int it = 0; it < 2; ++it) {
            int c = it * 256 + tid;
            int r = c >> 2, c8 = (c & 3) << 3;
            half8 v = *reinterpret_cast<const half8*>(comb + (size_t)(mbase + r) * 1024 + k0 + c8);
            *reinterpret_cast<half8*>(&At[r][c8]) = v;
        }
        // B: W_out fp32 -> fp16; 128 rows x 8 float4 chunks
#pragma unroll
        for (int it = 0; it < 4; ++it) {
            int c = it * 256 + tid;
            int r = c >> 3, cc = (c & 7) << 2;
            float4 vb = *reinterpret_cast<const float4*>(W_out + (size_t)(nbase + r) * 1024 + k0 + cc);
            half4 hb = {(f16)vb.x, (f16)vb.y, (f16)vb.z, (f16)vb.w};
            *reinterpret_cast<half4*>(&Bt[r][cc]) = hb;
        }
        __syncthreads();
        half8 a[4], b[4];
#pragma unroll
        for (int i = 0; i < 4; ++i) a[i] = *reinterpret_cast<half8*>(&At[wm + i * 16 + l15][quad * 8]);
#pragma unroll
        for (int j = 0; j < 4; ++j) b[j] = *reinterpret_cast<half8*>(&Bt[wn + j * 16 + l15][quad * 8]);
#pragma unroll
        for (int i = 0; i < 4; ++i)
#pragma unroll
            for (int j = 0; j < 4; ++j)
                acc[i][j] = MFMA16(a[i], b[j], acc[i][j]);
        __syncthreads();
    }
#pragma unroll
    for (int i = 0; i < 4; ++i)
#pragma unroll
        for (int j = 0; j < 4; ++j)
#pragma unroll
            for (int r = 0; r < 4; ++r)
                out[(size_t)(mbase + wm + i * 16 + quad * 4 + r) * 512 + nbase + wn + j * 16 + l15] =
                    acc[i][j][r];
}

extern "C" void kernel_launch(void* const* d_in, const int* in_sizes, int n_in,
                              void* d_out, int out_size, void* d_ws, size_t ws_size,
                              hipStream_t stream)
{
    const float* query = (const float*)d_in[0];
    const float* W_in  = (const float*)d_in[1];
    const float* W_out = (const float*)d_in[2];
    float* out = (float*)d_out;

    // ws layout: comb fp16 [32768][1024] (mix | q) = 64 MB, then qT fp16 [16][512][2048] = 32 MB
    f16* comb = (f16*)d_ws;
    f16* qT   = comb + (size_t)32768 * 1024;

    hipFuncSetAttribute(reinterpret_cast<const void*>(k_attn),
                        hipFuncAttributeMaxDynamicSharedMemorySize, 149504);

    k_qin<<<dim3(4, 256), 256, 0, stream>>>(query, W_in, comb, qT);
    k_attn<<<dim3(32, 16), 256, 149504, stream>>>(qT, comb);
    k_out<<<dim3(4, 256), 256, 0, stream>>>(comb, W_out, out);
}